// Round 9
// baseline (363.479 us; speedup 1.0000x reference)
//
#include <hip/hip_runtime.h>

#define V_NODES 327696
#define E_EDGES 1966080
#define C_DIM   64
#define G_NUM   4
#define EPS_GN  1e-5f
#define N_TILES (V_NODES/16)      // 20481 exact
#define SAGE_BLOCKS 2048
#define WAVES_TOTAL (SAGE_BLOCKS*4)
#define FILL_BLOCKS 512
#define H_BLOCKS 2048
#define NB_SCAN 1281              // ceil(V/256)
#define CH_SCAN2 6                // ceil(NB_SCAN/256)
#define PW 520                    // partial row width (floats)
#define STAT_BLOCKS 2048
#define STAT_WAVES (STAT_BLOCKS*4)     // 8192
#define TOTAL_F4 (V_NODES*16)          // 5243136 float4 chunks
#define SW_CHUNK 640                   // float4s per wave (40 nodes)
#define HIST_BLOCKS 960                // 960*256*8 = E
#define RED_BLOCKS 129                 // 129*4 = 516 entries
#define SROW 17                        // LDS stage: ch-major, stride 17 rows (16 + trash)
#define STAGE_PAD 1280                 // u32 per wave (>= 64*17=1088, 5x256 for zeroing)

typedef short bf16x8 __attribute__((ext_vector_type(8)));
typedef float f32x4  __attribute__((ext_vector_type(4)));
typedef unsigned uintx4 __attribute__((ext_vector_type(4)));
typedef int intx4 __attribute__((ext_vector_type(4)));

__device__ __forceinline__ unsigned short f2bf(float f) {   // RNE f32 -> bf16
    unsigned u = __float_as_uint(f);
    return (unsigned short)((u + 0x7FFFu + ((u >> 16) & 1u)) >> 16);
}
// monotone-u16 encoding of bf16 bits: order(enc)==order(value); enc>=0x007F>0
__device__ __forceinline__ unsigned short encbf(float f) {
    unsigned short b = f2bf(f);
    return b ^ (unsigned short)(0x8000u | ((b >> 15) * 0x7FFFu));
}
__device__ __forceinline__ unsigned decp(unsigned e) {      // packed decode x2
    unsigned s = e & 0x80008000u;
    unsigned m = (s >> 15) * 0x7FFFu;
    return e ^ ~m;
}

// ---------------------------------------------------------------------------
// K_pre (merged): blocks [0,HIST_BLOCKS) in-degree hist + rank (8 independent
// atomic-returns in flight); blocks [HIST_BLOCKS,..) per-(g,c) stats of x
// (wave-contiguous branch-free fast path, partial rows, no global atomics).
// Overlaps hist's atomic latency with stats' BW.
// ---------------------------------------------------------------------------
__global__ __launch_bounds__(256) void k_pre(const float* __restrict__ x,
                                             const int* __restrict__ batch,
                                             const int* __restrict__ ei,
                                             int* __restrict__ hist,
                                             unsigned short* __restrict__ rank,
                                             float* __restrict__ partial1) {
    __shared__ float red_s[256], red_q[256], red_c[G_NUM];
    if (blockIdx.x < HIST_BLOCKS) {
        const int t = blockIdx.x * 256 + threadIdx.x;
        const int* dst = ei + E_EDGES;
        const int e0 = t * 4;
        const int e1 = (E_EDGES / 2) + t * 4;
        intx4 a = *(const intx4*)(dst + e0);
        intx4 b = *(const intx4*)(dst + e1);
        int r0 = atomicAdd(&hist[a[0]], 1);
        int r1 = atomicAdd(&hist[a[1]], 1);
        int r2 = atomicAdd(&hist[a[2]], 1);
        int r3 = atomicAdd(&hist[a[3]], 1);
        int r4 = atomicAdd(&hist[b[0]], 1);
        int r5 = atomicAdd(&hist[b[1]], 1);
        int r6 = atomicAdd(&hist[b[2]], 1);
        int r7 = atomicAdd(&hist[b[3]], 1);
        ushort4 wa = { (unsigned short)r0, (unsigned short)r1,
                       (unsigned short)r2, (unsigned short)r3 };
        ushort4 wb = { (unsigned short)r4, (unsigned short)r5,
                       (unsigned short)r6, (unsigned short)r7 };
        *(ushort4*)(rank + e0) = wa;
        *(ushort4*)(rank + e1) = wb;
        return;
    }
    const int t = threadIdx.x;
    red_s[t] = 0.0f; red_q[t] = 0.0f;
    if (t < G_NUM) red_c[t] = 0.0f;
    __syncthreads();
    const int bid  = blockIdx.x - HIST_BLOCKS;
    const int w    = bid * 4 + (t >> 6);
    const int lane = t & 63;
    const int base = w * SW_CHUNK;
    const int end  = (w == STAT_WAVES - 1) ? TOTAL_F4 : base + SW_CHUNK;
    const int c4   = (lane & 15) << 2;
    const bool cntr = (lane & 15) == 0;
    const float4* x4p = (const float4*)x;
    const int g0 = batch[base >> 4];
    const int g1 = batch[(end - 1) >> 4];
    if (g0 == g1 && end == base + SW_CHUNK) {
        float4 su = {0,0,0,0}, qu = {0,0,0,0};
        #pragma unroll
        for (int it = 0; it < 10; it++) {
            float4 v = x4p[base + lane + it * 64];
            su.x += v.x; su.y += v.y; su.z += v.z; su.w += v.w;
            qu.x = fmaf(v.x, v.x, qu.x); qu.y = fmaf(v.y, v.y, qu.y);
            qu.z = fmaf(v.z, v.z, qu.z); qu.w = fmaf(v.w, v.w, qu.w);
        }
        int p = (g0 << 6) + c4;
        atomicAdd(&red_s[p],   su.x); atomicAdd(&red_q[p],   qu.x);
        atomicAdd(&red_s[p+1], su.y); atomicAdd(&red_q[p+1], qu.y);
        atomicAdd(&red_s[p+2], su.z); atomicAdd(&red_q[p+2], qu.z);
        atomicAdd(&red_s[p+3], su.w); atomicAdd(&red_q[p+3], qu.w);
        if (cntr) atomicAdd(&red_c[g0], 10.0f);
    } else {
        for (int idx = base + lane; idx < end; idx += 64) {
            float4 v = x4p[idx];
            int g = batch[idx >> 4];
            int p = (g << 6) + c4;
            atomicAdd(&red_s[p],   v.x); atomicAdd(&red_q[p],   v.x * v.x);
            atomicAdd(&red_s[p+1], v.y); atomicAdd(&red_q[p+1], v.y * v.y);
            atomicAdd(&red_s[p+2], v.z); atomicAdd(&red_q[p+2], v.z * v.z);
            atomicAdd(&red_s[p+3], v.w); atomicAdd(&red_q[p+3], v.w * v.w);
            if (cntr) atomicAdd(&red_c[g], 1.0f);
        }
    }
    __syncthreads();
    float* row = partial1 + (size_t)bid * PW;
    row[t] = red_s[t]; row[256 + t] = red_q[t];
    if (t < G_NUM) row[512 + t] = red_c[t];
}

// ---------------------------------------------------------------------------
// K_rs1 (merged): blocks [0,RED_BLOCKS) reduce partial1 -> sum1/sumsq1/cnt;
//                 blocks [RED_BLOCKS,..) per-256 block sums of hist -> bsum
// ---------------------------------------------------------------------------
__global__ __launch_bounds__(256) void k_rs1(const float* __restrict__ partial1,
                                             const int* __restrict__ hist,
                                             float* __restrict__ outs,
                                             float* __restrict__ outc,
                                             int* __restrict__ bsum) {
    if (blockIdx.x < RED_BLOCKS) {
        int e = blockIdx.x * 4 + (threadIdx.x >> 6);
        int lane = threadIdx.x & 63;
        if (e >= 516) return;
        float s = 0.0f;
        for (int b = lane; b < STAT_BLOCKS; b += 64) s += partial1[(size_t)b * PW + e];
        #pragma unroll
        for (int off = 1; off < 64; off <<= 1) s += __shfl_xor(s, off);
        if (lane == 0) { if (e < 512) outs[e] = s; else outc[e - 512] = s; }
        return;
    }
    __shared__ int s[256];
    int sb = blockIdx.x - RED_BLOCKS;
    int i = sb * 256 + threadIdx.x;
    s[threadIdx.x] = (i < V_NODES) ? hist[i] : 0;
    __syncthreads();
    for (int off = 128; off > 0; off >>= 1) {
        if (threadIdx.x < off) s[threadIdx.x] += s[threadIdx.x + off];
        __syncthreads();
    }
    if (threadIdx.x == 0) bsum[sb] = s[0];
}

// ---------------------------------------------------------------------------
// K_params: block 0 = GraphNorm-1 affine fold + swizzled weight prep;
//           block 1 = exclusive scan of the 1281 block sums
// ---------------------------------------------------------------------------
__global__ __launch_bounds__(256) void k_params(const float* __restrict__ sum,
                                                const float* __restrict__ sumsq,
                                                const float* __restrict__ cnt,
                                                const float* __restrict__ w,
                                                const float* __restrict__ b,
                                                const float* __restrict__ ms,
                                                float* __restrict__ scale,
                                                float* __restrict__ shift,
                                                const float* __restrict__ Wl,
                                                const float* __restrict__ Wr,
                                                char* __restrict__ gWsw,
                                                int* __restrict__ bsum) {
    if (blockIdx.x == 0) {
        int t = threadIdx.x;            // t = g*64 + c
        int g = t >> 6, c = t & 63;
        float n    = cnt[g];
        float mean = sum[t] / n;
        float msq  = sumsq[t] / n;
        float m    = ms[c];
        float var  = msq - 2.0f*m*mean*mean + m*m*mean*mean;
        float inv  = rsqrtf(var + EPS_GN);
        float sc   = w[c] * inv;
        scale[t] = sc;
        shift[t] = b[c] - mean * m * sc;
        for (int i = threadIdx.x; i < C_DIM*C_DIM; i += 256) {
            int k = i >> 6, col = i & 63;          // W[k][col]
            int boff = (col*128 + k*2) ^ ((col & 7) << 4);
            *(unsigned short*)(gWsw + boff)        = f2bf(Wl[i]);
            *(unsigned short*)(gWsw + 8192 + boff) = f2bf(Wr[i]);
        }
    } else {
        __shared__ int s[256];
        int t = threadIdx.x;
        int loc[CH_SCAN2];
        int mysum = 0;
        #pragma unroll
        for (int j = 0; j < CH_SCAN2; j++) {
            int idx = t * CH_SCAN2 + j;
            loc[j] = (idx < NB_SCAN) ? bsum[idx] : 0;
            mysum += loc[j];
        }
        s[t] = mysum;
        __syncthreads();
        for (int off = 1; off < 256; off <<= 1) {
            int tmp = (t >= off) ? s[t - off] : 0;
            __syncthreads();
            s[t] += tmp;
            __syncthreads();
        }
        int ex = s[t] - mysum;
        #pragma unroll
        for (int j = 0; j < CH_SCAN2; j++) {
            int idx = t * CH_SCAN2 + j;
            if (idx < NB_SCAN) { bsum[idx] = ex; ex += loc[j]; }
        }
    }
}

// ---------------------------------------------------------------------------
// K_scan3: per-block exclusive scan + block offset -> offs
// ---------------------------------------------------------------------------
__global__ __launch_bounds__(256) void k_scan3(const int* __restrict__ hist,
                                               const int* __restrict__ bsum,
                                               int* __restrict__ offs) {
    __shared__ int s[256];
    int t = threadIdx.x;
    int i = blockIdx.x * 256 + t;
    int v = (i < V_NODES) ? hist[i] : 0;
    s[t] = v;
    __syncthreads();
    for (int off = 1; off < 256; off <<= 1) {
        int tmp = (t >= off) ? s[t - off] : 0;
        __syncthreads();
        s[t] += tmp;
        __syncthreads();
    }
    int ex = s[t] - v + bsum[blockIdx.x];
    if (i < V_NODES) offs[i] = ex;
    if (i == 0) offs[V_NODES] = E_EDGES;
}

// ---------------------------------------------------------------------------
// K_h_fill (merged): fill blocks write packed slots (src | dst-row-in-tile<<27)
//                    atomic-free via rank; h blocks compute henc.
// ---------------------------------------------------------------------------
__global__ __launch_bounds__(256) void k_h_fill(const float* __restrict__ x,
                                                const int* __restrict__ batch,
                                                const float* __restrict__ scale1,
                                                const float* __restrict__ shift1,
                                                unsigned short* __restrict__ henc,
                                                const int* __restrict__ ei,
                                                const unsigned short* __restrict__ rank,
                                                const int* __restrict__ offs,
                                                int* __restrict__ slots) {
    if (blockIdx.x < FILL_BLOCKS) {
        int stride = FILL_BLOCKS * 256;
        for (int e = blockIdx.x * 256 + threadIdx.x; e < E_EDGES; e += stride) {
            int src = ei[e];
            int d   = ei[E_EDGES + e];
            slots[offs[d] + (int)rank[e]] = src | ((d & 15) << 27);
        }
        return;
    }
    __shared__ float sc[256], sh[256];
    sc[threadIdx.x] = scale1[threadIdx.x];
    sh[threadIdx.x] = shift1[threadIdx.x];
    __syncthreads();
    const int total = V_NODES * 16;
    int bid = blockIdx.x - FILL_BLOCKS;
    int stride = H_BLOCKS * 256;
    const float4* x4 = (const float4*)x;
    ushort4* h4 = (ushort4*)henc;
    for (int i = bid * 256 + threadIdx.x; i < total; i += stride) {
        int v  = i >> 4;
        int c4 = (i & 15) << 2;
        int g  = batch[v];
        int p  = (g << 6) | c4;
        float4 val = x4[i];
        ushort4 o;
        o.x = encbf(fmaf(val.x, sc[p],   sh[p]));
        o.y = encbf(fmaf(val.y, sc[p+1], sh[p+1]));
        o.z = encbf(fmaf(val.z, sc[p+2], sh[p+2]));
        o.w = encbf(fmaf(val.w, sc[p+3], sh[p+3]));
        h4[i] = o;
    }
}

// ---------------------------------------------------------------------------
// K_sage: line-local gather. Per tile: iterate the COMBINED CSR range
// (contiguous slots); per instr 8 edges x 8 lanes x 16B contiguous per row
// (16 cache lines/instr, not 64). Cross-lane max via LDS ds_max_u32 in
// ch-major [ch*17+row] layout (2-way bank alias = free). Then readback into
// MFMA A-frags, dual GEMM, residual/ReLU, stats2 partials.
// ---------------------------------------------------------------------------
__global__ __launch_bounds__(256) void k_sage(const unsigned short* __restrict__ henc,
                                              const float* __restrict__ x,
                                              const int* __restrict__ batch,
                                              const int* __restrict__ offs,
                                              const int* __restrict__ slots,
                                              const char* __restrict__ gWsw,
                                              const float* __restrict__ bl,
                                              float* __restrict__ out,
                                              float* __restrict__ partial2) {
    __shared__ char lds_w[16384];              // Wl swizzled at 0, Wr at 8192
    __shared__ float red_s[256], red_q[256];
    __shared__ unsigned stage[4][STAGE_PAD];   // per-wave gather staging (20.5 KB)
    {
        const float4* wsrc = (const float4*)gWsw;
        float4* wdst = (float4*)lds_w;
        for (int t = threadIdx.x; t < 1024; t += 256) wdst[t] = wsrc[t];
    }
    red_s[threadIdx.x] = 0.0f; red_q[threadIdx.x] = 0.0f;
    __syncthreads();

    const int lane = threadIdx.x & 63;
    const int wid  = threadIdx.x >> 6;
    const int lg = lane >> 4, lr = lane & 15;
    const int es = lane >> 3;                  // edge slot 0..7
    const int ss = lane & 7;                   // channel octet 0..7
    const char* hbase = (const char*)henc;
    unsigned* st_w = &stage[wid][0];

    float blv[4];
    #pragma unroll
    for (int cb = 0; cb < 4; cb++) blv[cb] = bl[cb*16 + lr];

    float su[4] = {0,0,0,0}, qu[4] = {0,0,0,0};
    int gc = -1;

    const int gwave = blockIdx.x * 4 + wid;
    for (int tile = gwave; tile < N_TILES; tile += WAVES_TOTAL) {
        const int rbase = tile << 4;
        // zero staging (linear b128, conflict-free)
        #pragma unroll
        for (int z = 0; z < 5; z++)
            *(uintx4*)(st_w + z*256 + lane*4) = (uintx4){0,0,0,0};
        // per-row ranges (lanes lg-redundant over lr)
        int o_lo = offs[rbase + lr];
        int o_hi = offs[rbase + lr + 1];
        bool has = o_hi > o_lo;
        int st_t = __shfl(o_lo, 0);
        int en_t = __shfl(o_hi, 15);
        __builtin_amdgcn_wave_barrier();
        // ---- combined gather: 8 edges/iter, each edge = 8 lanes x 16B ----
        for (int i = st_t; i < en_t; i += 8) {
            int ii = i + es;
            unsigned sv = (ii < en_t) ? (unsigned)slots[ii]
                                      : (0x80000000u | (unsigned)V_NODES); // row16 trash
            unsigned src = sv & 0x07FFFFFFu;
            unsigned row = sv >> 27;                        // 0..15 valid, 16 trash
            uintx4 hv = *(const uintx4*)(hbase + ((size_t)src << 7) + ss*16);
            unsigned cb0 = (ss << 3);                       // first channel of octet
            #pragma unroll
            for (int j = 0; j < 4; j++) {
                atomicMax(&st_w[(cb0 + 2*j    ) * SROW + row], hv[j] & 0xFFFFu);
                atomicMax(&st_w[(cb0 + 2*j + 1) * SROW + row], hv[j] >> 16);
            }
        }
        __builtin_amdgcn_wave_barrier();
        // ---- readback row lr, channels lg*8..+7 and 32+lg*8..+7 ----
        unsigned e0[8], e1[8];
        #pragma unroll
        for (int jj = 0; jj < 8; jj++) {
            e0[jj] = st_w[(lg*8 + jj) * SROW + lr];
            e1[jj] = st_w[(32 + lg*8 + jj) * SROW + lr];
        }
        __builtin_amdgcn_wave_barrier();
        uintx4 d0, d1;
        d0[0] = e0[0] | (e0[1] << 16); d0[1] = e0[2] | (e0[3] << 16);
        d0[2] = e0[4] | (e0[5] << 16); d0[3] = e0[6] | (e0[7] << 16);
        d1[0] = e1[0] | (e1[1] << 16); d1[1] = e1[2] | (e1[3] << 16);
        d1[2] = e1[4] | (e1[5] << 16); d1[3] = e1[6] | (e1[7] << 16);
        // root-h fragments from global
        const char* hr = hbase + ((size_t)(rbase + lr) << 7);
        uintx4 r0 = *(const uintx4*)(hr + lg*16);
        uintx4 r1 = *(const uintx4*)(hr + 64 + lg*16);
        #pragma unroll
        for (int j = 0; j < 4; j++) {
            d0[j] = has ? decp(d0[j]) : 0u;
            d1[j] = has ? decp(d1[j]) : 0u;
            r0[j] = decp(r0[j]);
            r1[j] = decp(r1[j]);
        }
        bf16x8 a_agg0 = __builtin_bit_cast(bf16x8, d0);
        bf16x8 a_agg1 = __builtin_bit_cast(bf16x8, d1);
        bf16x8 a_h0   = __builtin_bit_cast(bf16x8, r0);
        bf16x8 a_h1   = __builtin_bit_cast(bf16x8, r1);

        // ---- dual GEMM via MFMA, B-frags from swizzled LDS ----
        f32x4 acc[4];
        #pragma unroll
        for (int cb = 0; cb < 4; cb++) {
            acc[cb] = (f32x4){0.f,0.f,0.f,0.f};
            int wrow = cb*16 + lr;
            int sw   = (wrow & 7) << 4;
            int o0   = (wrow*128 +      lg*16) ^ sw;
            int o1   = (wrow*128 + 64 + lg*16) ^ sw;
            bf16x8 wl0 = *(const bf16x8*)(lds_w + o0);
            bf16x8 wl1 = *(const bf16x8*)(lds_w + o1);
            bf16x8 wr0 = *(const bf16x8*)(lds_w + 8192 + o0);
            bf16x8 wr1 = *(const bf16x8*)(lds_w + 8192 + o1);
            acc[cb] = __builtin_amdgcn_mfma_f32_16x16x32_bf16(a_agg0, wl0, acc[cb], 0,0,0);
            acc[cb] = __builtin_amdgcn_mfma_f32_16x16x32_bf16(a_agg1, wl1, acc[cb], 0,0,0);
            acc[cb] = __builtin_amdgcn_mfma_f32_16x16x32_bf16(a_h0,   wr0, acc[cb], 0,0,0);
            acc[cb] = __builtin_amdgcn_mfma_f32_16x16x32_bf16(a_h1,   wr1, acc[cb], 0,0,0);
        }

        // ---- epilogue: bias + residual + ReLU + write + stats ----
        int g0 = batch[rbase], g15 = batch[rbase + 15];
        if (g0 == g15) {
            if (g0 != gc) {
                if (gc >= 0) {
                    #pragma unroll
                    for (int cb = 0; cb < 4; cb++) {
                        atomicAdd(&red_s[(gc<<6) + cb*16 + lr], su[cb]);
                        atomicAdd(&red_q[(gc<<6) + cb*16 + lr], qu[cb]);
                        su[cb] = 0.0f; qu[cb] = 0.0f;
                    }
                }
                gc = g0;
            }
            #pragma unroll
            for (int r = 0; r < 4; r++) {
                int row = rbase + lg*4 + r;
                #pragma unroll
                for (int cb = 0; cb < 4; cb++) {
                    int col = cb*16 + lr;
                    float xv = x[(size_t)row * C_DIM + col];
                    float o  = fmaxf(xv + acc[cb][r] + blv[cb], 0.0f);
                    out[(size_t)row * C_DIM + col] = o;
                    su[cb] += o; qu[cb] = fmaf(o, o, qu[cb]);
                }
            }
        } else {                                   // boundary tile (3 of 20481)
            #pragma unroll
            for (int r = 0; r < 4; r++) {
                int row = rbase + lg*4 + r;
                int g   = batch[row];
                #pragma unroll
                for (int cb = 0; cb < 4; cb++) {
                    int col = cb*16 + lr;
                    float xv = x[(size_t)row * C_DIM + col];
                    float o  = fmaxf(xv + acc[cb][r] + blv[cb], 0.0f);
                    out[(size_t)row * C_DIM + col] = o;
                    int p = (g << 6) | col;
                    atomicAdd(&red_s[p], o);
                    atomicAdd(&red_q[p], o * o);
                }
            }
        }
    }
    if (gc >= 0) {
        #pragma unroll
        for (int cb = 0; cb < 4; cb++) {
            atomicAdd(&red_s[(gc<<6) + cb*16 + lr], su[cb]);
            atomicAdd(&red_q[(gc<<6) + cb*16 + lr], qu[cb]);
        }
    }
    __syncthreads();
    float* row = partial2 + (size_t)blockIdx.x * PW;
    row[threadIdx.x]       = red_s[threadIdx.x];
    row[256 + threadIdx.x] = red_q[threadIdx.x];
}

// ---------------------------------------------------------------------------
// K_red2p: reduce partial2 AND fold GraphNorm-2 params directly (wave/(g,c))
// ---------------------------------------------------------------------------
__global__ __launch_bounds__(256) void k_red2p(const float* __restrict__ partial2,
                                               const float* __restrict__ cnt,
                                               const float* __restrict__ w,
                                               const float* __restrict__ b,
                                               const float* __restrict__ ms,
                                               float* __restrict__ scale2,
                                               float* __restrict__ shift2) {
    int e = blockIdx.x * 4 + (threadIdx.x >> 6);    // 0..255 = g*64+c
    int lane = threadIdx.x & 63;
    float s = 0.0f, q = 0.0f;
    for (int bb = lane; bb < SAGE_BLOCKS; bb += 64) {
        s += partial2[(size_t)bb * PW + e];
        q += partial2[(size_t)bb * PW + 256 + e];
    }
    #pragma unroll
    for (int off = 1; off < 64; off <<= 1) {
        s += __shfl_xor(s, off);
        q += __shfl_xor(q, off);
    }
    if (lane == 0) {
        int g = e >> 6, c = e & 63;
        float n    = cnt[g];
        float mean = s / n;
        float msq  = q / n;
        float m    = ms[c];
        float var  = msq - 2.0f*m*mean*mean + m*m*mean*mean;
        float inv  = rsqrtf(var + EPS_GN);
        float sc   = w[c] * inv;
        scale2[e] = sc;
        shift2[e] = b[c] - mean * m * sc;
    }
}

// ---------------------------------------------------------------------------
// K_final: in-place final GraphNorm affine on d_out (float4 vectorized)
// ---------------------------------------------------------------------------
__global__ __launch_bounds__(256) void k_final(float* __restrict__ out,
                                               const int* __restrict__ batch,
                                               const float* __restrict__ scale2,
                                               const float* __restrict__ shift2) {
    __shared__ float sc[256], sh[256];
    sc[threadIdx.x] = scale2[threadIdx.x];
    sh[threadIdx.x] = shift2[threadIdx.x];
    __syncthreads();
    const int total = V_NODES * 16;
    int stride = gridDim.x * 256;
    float4* o4 = (float4*)out;
    for (int i = blockIdx.x * 256 + threadIdx.x; i < total; i += stride) {
        int v  = i >> 4;
        int c4 = (i & 15) << 2;
        int g  = batch[v];
        int p  = (g << 6) | c4;
        float4 val = o4[i];
        val.x = fmaf(val.x, sc[p],   sh[p]);
        val.y = fmaf(val.y, sc[p+1], sh[p+1]);
        val.z = fmaf(val.z, sc[p+2], sh[p+2]);
        val.w = fmaf(val.w, sc[p+3], sh[p+3]);
        o4[i] = val;
    }
}

// ---------------------------------------------------------------------------
extern "C" void kernel_launch(void* const* d_in, const int* in_sizes, int n_in,
                              void* d_out, int out_size, void* d_ws, size_t ws_size,
                              hipStream_t stream) {
    const float* x     = (const float*)d_in[0];
    const int*   ei    = (const int*)  d_in[1];
    const int*   batch = (const int*)  d_in[2];
    const float* n1w   = (const float*)d_in[3];
    const float* n1b   = (const float*)d_in[4];
    const float* n1ms  = (const float*)d_in[5];
    const float* Wl    = (const float*)d_in[6];
    const float* blv   = (const float*)d_in[7];
    const float* Wr    = (const float*)d_in[8];
    const float* n2w   = (const float*)d_in[9];
    const float* n2b   = (const float*)d_in[10];
    const float* n2ms  = (const float*)d_in[11];
    float* out = (float*)d_out;

    // ---- workspace layout (~66 MB; ws >= 84 MB proven in round 1) ----
    char* w = (char*)d_ws;
    unsigned short* henc = (unsigned short*)w; w += (size_t)(V_NODES + 1) * C_DIM * 2; // +dummy row (zeroed)
    int* slots           = (int*)w;            w += (size_t)E_EDGES * 4 + 64;
    int* hist            = (int*)w;            w += (size_t)V_NODES * 4;
    int* offs            = (int*)w;            w += (size_t)(V_NODES + 1) * 4 + 12;
    unsigned short* rank = (unsigned short*)w; w += (size_t)E_EDGES * 2;
    int* bsum            = (int*)w;            w += 1536 * 4;
    char* gWsw           = w;                  w += 16384;
    float* partial1      = (float*)w;          w += (size_t)STAT_BLOCKS * PW * 4;
    float* partial2      = (float*)w;          w += (size_t)SAGE_BLOCKS * PW * 4;
    float* stats  = (float*)w;
    float* sum1   = stats;          // 256
    float* sumsq1 = stats + 256;    // 256
    float* cnt    = stats + 512;    // 4 (+pad 60)
    float* scale1 = stats + 576;
    float* shift1 = stats + 832;
    float* scale2 = stats + 1088;
    float* shift2 = stats + 1344;   // end 1600 floats

    hipMemsetAsync(hist, 0, (size_t)V_NODES * sizeof(int), stream);
    hipMemsetAsync(henc + (size_t)V_NODES * C_DIM, 0, C_DIM * 2, stream); // dummy row

    k_pre   <<<HIST_BLOCKS + STAT_BLOCKS, 256, 0, stream>>>(x, batch, ei, hist, rank, partial1);
    k_rs1   <<<RED_BLOCKS + NB_SCAN, 256, 0, stream>>>(partial1, hist, sum1, cnt, bsum);
    k_params<<<2,    256, 0, stream>>>(sum1, sumsq1, cnt, n1w, n1b, n1ms,
                                       scale1, shift1, Wl, Wr, gWsw, bsum);
    k_scan3 <<<NB_SCAN, 256, 0, stream>>>(hist, bsum, offs);
    k_h_fill<<<FILL_BLOCKS + H_BLOCKS, 256, 0, stream>>>(x, batch, scale1, shift1,
                                       henc, ei, rank, offs, slots);
    k_sage  <<<SAGE_BLOCKS, 256, 0, stream>>>(henc, x, batch, offs, slots,
                                       gWsw, blv, out, partial2);
    k_red2p <<<64,   256, 0, stream>>>(partial2, cnt, n2w, n2b, n2ms, scale2, shift2);
    k_final <<<2048, 256, 0, stream>>>(out, batch, scale2, shift2);
}